// Round 14
// baseline (126.181 us; speedup 1.0000x reference)
//
#include <hip/hip_runtime.h>

#define DIM 128
#define CAP 96              // csr slots per node (mean in-deg 32; ovf fallback)
#define BCAP 10240          // region entries per 256-node bucket (mean ~8163, +23 sigma)
#define EPB 4096            // edges per scatter block
#define EPT 16              // edges per thread (EPB/256)
#define GL 16               // lanes per node group in conv kernels (uint2/lane)
#define OVFD_CAP 32768
#define OVFS_CAP 32768

typedef float f32x2 __attribute__((ext_vector_type(2)));

// ---- fp8 e4m3 (OCP, gfx950 HW cvt) helpers ----
template <bool HI>
__device__ __forceinline__ float2 fp8x2_to_f32(unsigned u) {
    f32x2 r = __builtin_amdgcn_cvt_pk_f32_fp8((int)u, HI);
    return make_float2(r.x, r.y);
}
__device__ __forceinline__ unsigned short f32_to_fp8x2(float a, float b) {
    return (unsigned short)(__builtin_amdgcn_cvt_pk_fp8_f32(a, b, 0, false) & 0xFFFF);
}

// Zero the 520-int header (gcursD/gcursS/ovf counters).
__global__ void zero_hdr(int* __restrict__ hdr) {
    int i = threadIdx.x;
    hdr[i] = 0;
    hdr[i + 260] = 0;
    if (i < 8) hdr[i + 512] = 0;
}

// Roles: [0,nb_scat): register-staged counting-sort of EPB edges into 256-node buckets
//        [..,+nb_norm): row L2-normalize features -> fp8 Xb8
//        [..,+nb_copy): preference passthrough (float4)
__global__ void __launch_bounds__(256) prep_kernel(
        const float* __restrict__ features, const float* __restrict__ preference,
        const int* __restrict__ src, const int* __restrict__ dst,
        unsigned short* __restrict__ Xb8,
        unsigned* __restrict__ regionD, unsigned char* __restrict__ regionS,
        int* __restrict__ gcursD, int* __restrict__ gcursS,
        int* __restrict__ ovfD_n, int2* __restrict__ ovfD,
        int* __restrict__ ovfS_n, int* __restrict__ ovfS,
        float* __restrict__ out_pref,
        int N, int E, int NU, int nb, int nb_scat, int nb_norm) {
    __shared__ unsigned histD[256], histS[256];
    __shared__ unsigned scanD[256], scanS[256];
    __shared__ unsigned cursD[256], cursS[256];   // cursors during stage, bases after claim
    __shared__ unsigned wsumD[4], wsumS[4];
    __shared__ unsigned stageD[EPB];              // 16 KB: (bk<<24)|(dLow<<16)|src16
    __shared__ unsigned short stageS[EPB];        // 8 KB: (bk<<8)|sLow
    int b = blockIdx.x, tid = threadIdx.x;

    if (b < nb_scat) {
        int e0 = b * EPB;
        int m = min(E - e0, EPB);
        histD[tid] = 0; histS[tid] = 0;
        unsigned packed[EPT];
        #pragma unroll
        for (int k = 0; k < EPT; ++k) {
            int j = tid + (k << 8);
            packed[k] = 0xFFFFFFFFu;
            if (j < m) {
                int s = src[e0 + j], d = dst[e0 + j];
                if (s != d) packed[k] = ((unsigned)d << 16) | (unsigned)s;
            }
        }
        __syncthreads();
        #pragma unroll
        for (int k = 0; k < EPT; ++k) {
            unsigned pk = packed[k];
            if (pk != 0xFFFFFFFFu) {
                atomicAdd(&histD[(pk >> 24)], 1u);
                atomicAdd(&histS[(pk >> 8) & 0xFFu], 1u);
            }
        }
        __syncthreads();
        {   // parallel exclusive scan of 256 bins (both hists)
            int lane = tid & 63, wid = tid >> 6;
            unsigned vD = histD[tid], vS = histS[tid];
            unsigned iD = vD, iS = vS;
            #pragma unroll
            for (int off = 1; off < 64; off <<= 1) {
                unsigned tD = __shfl_up(iD, off, 64);
                unsigned tS = __shfl_up(iS, off, 64);
                if (lane >= off) { iD += tD; iS += tS; }
            }
            if (lane == 63) { wsumD[wid] = iD; wsumS[wid] = iS; }
            __syncthreads();
            if (tid == 0) { unsigned a = 0; for (int i = 0; i < 4; ++i) { unsigned t = wsumD[i]; wsumD[i] = a; a += t; } }
            if (tid == 64){ unsigned a = 0; for (int i = 0; i < 4; ++i) { unsigned t = wsumS[i]; wsumS[i] = a; a += t; } }
            __syncthreads();
            unsigned eD = iD - vD + wsumD[wid];
            unsigned eS = iS - vS + wsumS[wid];
            scanD[tid] = eD; scanS[tid] = eS;
            cursD[tid] = eD; cursS[tid] = eS;
        }
        __syncthreads();
        #pragma unroll
        for (int k = 0; k < EPT; ++k) {
            unsigned pk = packed[k];
            if (pk != 0xFFFFFFFFu) {
                unsigned bkD = pk >> 24;
                unsigned p = atomicAdd(&cursD[bkD], 1u);
                stageD[p] = (bkD << 24) | ((pk >> 16 & 0xFFu) << 16) | (pk & 0xFFFFu);
                unsigned bkS = (pk >> 8) & 0xFFu;
                unsigned q = atomicAdd(&cursS[bkS], 1u);
                stageS[q] = (unsigned short)((bkS << 8) | (pk & 0xFFu));
            }
        }
        __syncthreads();
        if (tid < nb) {   // claim contiguous global runs (reuse curs as base)
            unsigned c = histD[tid];
            cursD[tid] = c ? (unsigned)atomicAdd(&gcursD[tid], (int)c) : 0u;
            unsigned c2 = histS[tid];
            cursS[tid] = c2 ? (unsigned)atomicAdd(&gcursS[tid], (int)c2) : 0u;
        }
        __syncthreads();
        int mD = (int)(scanD[255] + histD[255]);
        for (int j = tid; j < mD; j += 256) {   // one-pass flush D
            unsigned ent = stageD[j];
            unsigned bk = ent >> 24;
            unsigned gp = cursD[bk] + (unsigned)j - scanD[bk];
            if (gp < BCAP) regionD[(size_t)bk * BCAP + gp] = ent & 0x00FFFFFFu;
            else {
                int o = atomicAdd(ovfD_n, 1);
                if (o < OVFD_CAP) ovfD[o] = make_int2((int)(ent & 0xFFFFu),
                                                      (int)((bk << 8) | ((ent >> 16) & 0xFFu)));
            }
        }
        int mS = (int)(scanS[255] + histS[255]);
        for (int j = tid; j < mS; j += 256) {   // one-pass flush S
            unsigned ent = stageS[j];
            unsigned bk = ent >> 8;
            unsigned gp = cursS[bk] + (unsigned)j - scanS[bk];
            if (gp < BCAP) regionS[(size_t)bk * BCAP + gp] = (unsigned char)(ent & 0xFFu);
            else {
                int o = atomicAdd(ovfS_n, 1);
                if (o < OVFS_CAP) ovfS[o] = (int)ent;
            }
        }
        return;
    }
    b -= nb_scat;
    if (b < nb_norm) {
        int t = b * 256 + tid;
        int row = t >> 6;
        if (row < N) {
            int lane = t & 63;
            float2 v = ((const float2*)(features + (size_t)row * DIM))[lane];
            float ss = v.x * v.x + v.y * v.y;
            #pragma unroll
            for (int off = 32; off >= 1; off >>= 1) ss += __shfl_xor(ss, off, 64);
            float scale = 1.0f / fmaxf(sqrtf(ss), 1e-12f);
            Xb8[(size_t)row * 64 + lane] = f32_to_fp8x2(v.x * scale, v.y * scale);
        }
        return;
    }
    b -= nb_norm;
    {
        int i = b * 256 + tid;
        int n4 = NU * DIM / 4;
        if (i < n4) ((float4*)out_pref)[i] = ((const float4*)preference)[i];
    }
}

// Roles: [0,nb): per-dst-bucket slot assignment -> csr + cnt; [nb,2nb): src-degree -> dis.
__global__ void __launch_bounds__(256) finalize_kernel(
        const unsigned* __restrict__ regionD, const unsigned char* __restrict__ regionS,
        const int* __restrict__ gcursD, const int* __restrict__ gcursS,
        unsigned short* __restrict__ csr, int* __restrict__ cnt, float* __restrict__ dis,
        int* __restrict__ ovfD_n, int2* __restrict__ ovfD,
        const int* __restrict__ ovfS_n, const int* __restrict__ ovfS, int N, int nb) {
    __shared__ unsigned c256[256];
    int b = blockIdx.x, tid = threadIdx.x;
    if (b < nb) {           // dst role
        c256[tid] = 0;
        __syncthreads();
        int m = min(gcursD[b], BCAP);
        for (int j = tid; j < m; j += 256) {
            unsigned ent = regionD[(size_t)b * BCAP + j];
            unsigned dLow = ent >> 16;
            int s = (int)(ent & 0xFFFFu);
            unsigned pos = atomicAdd(&c256[dLow], 1u);
            int node = (b << 8) | (int)dLow;
            if (pos < CAP) csr[(size_t)node * CAP + pos] = (unsigned short)s;
            else {
                int o = atomicAdd(ovfD_n, 1);
                if (o < OVFD_CAP) ovfD[o] = make_int2(s, node);
            }
        }
        __syncthreads();
        int node = (b << 8) | tid;
        if (node < N) cnt[node] = (int)c256[tid];
        return;
    }
    b -= nb;
    {                       // src role
        c256[tid] = 0;
        __syncthreads();
        int m = min(gcursS[b], BCAP);
        for (int j = tid; j < m; j += 256)
            atomicAdd(&c256[regionS[(size_t)b * BCAP + j]], 1u);
        __syncthreads();
        int on = min(*ovfS_n, OVFS_CAP);    // practically 0
        for (int k = tid; k < on; k += 256) {
            int v = ovfS[k];
            if ((v >> 8) == b) atomicAdd(&c256[v & 255], 1u);
        }
        __syncthreads();
        int node = (b << 8) | tid;
        if (node < N) {
            unsigned dg = c256[tid];
            dis[node] = dg ? rsqrtf((float)dg) : 0.0f;
        }
    }
}

// Accumulate 8 dims (one uint2 = 8 fp8) into acc[0..7]
__device__ __forceinline__ void acc8(float (&acc)[8], uint2 uv, float wt) {
    float2 q0 = fp8x2_to_f32<false>(uv.x), q1 = fp8x2_to_f32<true>(uv.x);
    float2 q2 = fp8x2_to_f32<false>(uv.y), q3 = fp8x2_to_f32<true>(uv.y);
    acc[0] += wt * q0.x; acc[1] += wt * q0.y;
    acc[2] += wt * q1.x; acc[3] += wt * q1.y;
    acc[4] += wt * q2.x; acc[5] += wt * q2.y;
    acc[6] += wt * q3.x; acc[7] += wt * q3.y;
}

// 16-lane-group gather, 4-deep edge unroll + batch-pipelined csr/weight preload:
// next batch's (src,weight) loads issue before current batch's 16 edges consume.
__device__ __forceinline__ void gather_node16(const uint2* __restrict__ X8,
                                              const unsigned short* __restrict__ csr,
                                              const int* __restrict__ cnt,
                                              const float* __restrict__ dis,
                                              const int* __restrict__ ovfD_n,
                                              const int2* __restrict__ ovfD,
                                              int node, int lane, float (&a)[8]) {
    int c = min(cnt[node], CAP);
    float dd = dis[node];
    size_t base = (size_t)node * CAP;
    float b8[8];
    #pragma unroll
    for (int j = 0; j < 8; ++j) { a[j] = 0.0f; b8[j] = 0.0f; }
    int sl = 0; float wl = 0.0f;
    if (lane < min(c, GL)) { sl = csr[base + lane]; wl = dis[sl] * dd; }
    for (int b0 = 0; b0 < c; b0 += GL) {
        // preload next batch before consuming current
        int mn = min(c - b0 - GL, GL);
        int sl_n = 0; float wl_n = 0.0f;
        if (lane < mn) { sl_n = csr[base + b0 + GL + lane]; wl_n = dis[sl_n] * dd; }
        int m = min(c - b0, GL);
        int i = 0;
        for (; i + 3 < m; i += 4) {
            int s0 = __shfl(sl, i, GL),     s1 = __shfl(sl, i + 1, GL);
            int s2 = __shfl(sl, i + 2, GL), s3 = __shfl(sl, i + 3, GL);
            float w0 = __shfl(wl, i, GL),     w1 = __shfl(wl, i + 1, GL);
            float w2 = __shfl(wl, i + 2, GL), w3 = __shfl(wl, i + 3, GL);
            uint2 u0 = X8[(size_t)s0 * GL + lane];
            uint2 u1 = X8[(size_t)s1 * GL + lane];
            uint2 u2 = X8[(size_t)s2 * GL + lane];
            uint2 u3 = X8[(size_t)s3 * GL + lane];
            acc8(a, u0, w0);
            acc8(b8, u1, w1);
            acc8(a, u2, w2);
            acc8(b8, u3, w3);
        }
        for (; i < m; ++i) {
            int s0 = __shfl(sl, i, GL);
            float w0 = __shfl(wl, i, GL);
            uint2 u0 = X8[(size_t)s0 * GL + lane];
            acc8(a, u0, w0);
        }
        sl = sl_n; wl = wl_n;
    }
    #pragma unroll
    for (int j = 0; j < 8; ++j) a[j] += b8[j];
    int on = min(*ovfD_n, OVFD_CAP);   // practically 0; formal correctness
    for (int k = 0; k < on; ++k) {
        int2 eo = ovfD[k];
        if (eo.y == node) {
            float w = dis[eo.x] * dd;
            uint2 u = X8[(size_t)eo.x * GL + lane];
            acc8(a, u, w);
        }
    }
}

__global__ void __launch_bounds__(256) conv1_kernel(
        const uint2* __restrict__ Xb8, const unsigned short* __restrict__ csr,
        const int* __restrict__ cnt, const float* __restrict__ dis,
        const int* __restrict__ ovfD_n, const int2* __restrict__ ovfD,
        uint2* __restrict__ Hb8, int n) {
    int t = blockIdx.x * 256 + threadIdx.x;
    int node = t >> 4;
    if (node >= n) return;
    int lane = threadIdx.x & (GL - 1);
    float a[8];
    gather_node16(Xb8, csr, cnt, dis, ovfD_n, ovfD, node, lane, a);
    unsigned lo = (unsigned)__builtin_amdgcn_cvt_pk_fp8_f32(a[0], a[1], 0, false);
    lo = (unsigned)__builtin_amdgcn_cvt_pk_fp8_f32(a[2], a[3], (int)lo, true);
    unsigned hi = (unsigned)__builtin_amdgcn_cvt_pk_fp8_f32(a[4], a[5], 0, false);
    hi = (unsigned)__builtin_amdgcn_cvt_pk_fp8_f32(a[6], a[7], (int)hi, true);
    Hb8[(size_t)node * GL + lane] = make_uint2(lo, hi);
}

// out = conv(h) + h + x, with h and x read from the fp8 rows (no features re-read).
__global__ void __launch_bounds__(256) conv2_kernel(
        const uint2* __restrict__ Hb8, const uint2* __restrict__ Xb8,
        const unsigned short* __restrict__ csr,
        const int* __restrict__ cnt, const float* __restrict__ dis,
        const int* __restrict__ ovfD_n, const int2* __restrict__ ovfD,
        float* __restrict__ out, int n) {
    int t = blockIdx.x * 256 + threadIdx.x;
    int node = t >> 4;
    if (node >= n) return;
    int lane = threadIdx.x & (GL - 1);
    float a[8];
    gather_node16(Hb8, csr, cnt, dis, ovfD_n, ovfD, node, lane, a);
    uint2 hu = Hb8[(size_t)node * GL + lane];
    uint2 xu = Xb8[(size_t)node * GL + lane];
    float2 h0 = fp8x2_to_f32<false>(hu.x), h1 = fp8x2_to_f32<true>(hu.x);
    float2 h2 = fp8x2_to_f32<false>(hu.y), h3 = fp8x2_to_f32<true>(hu.y);
    float2 x0 = fp8x2_to_f32<false>(xu.x), x1 = fp8x2_to_f32<true>(xu.x);
    float2 x2 = fp8x2_to_f32<false>(xu.y), x3 = fp8x2_to_f32<true>(xu.y);
    float4 o0, o1;
    o0.x = a[0] + h0.x + x0.x; o0.y = a[1] + h0.y + x0.y;
    o0.z = a[2] + h1.x + x1.x; o0.w = a[3] + h1.y + x1.y;
    o1.x = a[4] + h2.x + x2.x; o1.y = a[5] + h2.y + x2.y;
    o1.z = a[6] + h3.x + x3.x; o1.w = a[7] + h3.y + x3.y;
    float* orow = out + (size_t)node * DIM + lane * 8;
    *(float4*)orow = o0;
    *(float4*)(orow + 4) = o1;
}

extern "C" void kernel_launch(void* const* d_in, const int* in_sizes, int n_in,
                              void* d_out, int out_size, void* d_ws, size_t ws_size,
                              hipStream_t stream) {
    const float* features   = (const float*)d_in[0];
    const float* preference = (const float*)d_in[1];
    const int*   edge_index = (const int*)d_in[2];

    const int N  = in_sizes[0] / DIM;   // 50000
    const int NU = in_sizes[1] / DIM;   // 10000
    const int E  = in_sizes[2] / 2;     // 1600000

    const int* src = edge_index;
    const int* dst = edge_index + E;
    float* out = (float*)d_out;

    const int nb = (N + 255) / 256;     // 196 node buckets

    // workspace layout (~34 MB; ws >= 55 MB proven in round 2)
    char* p = (char*)d_ws;
    unsigned short* Xb8 = (unsigned short*)p; p += (size_t)N * 64 * sizeof(unsigned short);
    unsigned short* Hb8 = (unsigned short*)p; p += (size_t)N * 64 * sizeof(unsigned short);
    unsigned short* csr = (unsigned short*)p; p += (size_t)N * CAP * sizeof(unsigned short);
    unsigned* regionD = (unsigned*)p;         p += (size_t)nb * BCAP * sizeof(unsigned);
    unsigned char* regionS = (unsigned char*)p; p += (size_t)nb * BCAP;
    p = (char*)(((size_t)p + 15) & ~(size_t)15);
    int* cnt = (int*)p;                       p += (size_t)N * sizeof(int);
    float* dis = (float*)p;                   p += (size_t)N * sizeof(float);
    int* hdr = (int*)p;                       p += 520 * sizeof(int);
    int* gcursD = hdr;            // 256 ints
    int* gcursS = hdr + 260;      // 256 ints
    int* ovfD_n = hdr + 516;
    int* ovfS_n = hdr + 517;
    int2* ovfD = (int2*)p;                    p += (size_t)OVFD_CAP * sizeof(int2);
    int* ovfS = (int*)p;                      p += (size_t)OVFS_CAP * sizeof(int);

    zero_hdr<<<1, 256, 0, stream>>>(hdr);

    int nb_scat = (E + EPB - 1) / EPB;
    int nb_norm = (N * 64 + 255) / 256;
    int nb_copy = (NU * DIM / 4 + 255) / 256;
    prep_kernel<<<nb_scat + nb_norm + nb_copy, 256, 0, stream>>>(
        features, preference, src, dst, Xb8, regionD, regionS,
        gcursD, gcursS, ovfD_n, ovfD, ovfS_n, ovfS,
        out + (size_t)N * DIM, N, E, NU, nb, nb_scat, nb_norm);

    finalize_kernel<<<2 * nb, 256, 0, stream>>>(
        regionD, regionS, gcursD, gcursS, csr, cnt, dis,
        ovfD_n, ovfD, ovfS_n, ovfS, N, nb);

    int cblocks = (N * GL + 255) / 256;
    conv1_kernel<<<cblocks, 256, 0, stream>>>((const uint2*)Xb8, csr, cnt, dis,
                                              ovfD_n, ovfD, (uint2*)Hb8, N);
    conv2_kernel<<<cblocks, 256, 0, stream>>>((const uint2*)Hb8, (const uint2*)Xb8,
                                              csr, cnt, dis, ovfD_n, ovfD, out, N);
}

// Round 15
// 117.123 us; speedup vs baseline: 1.0773x; 1.0773x over previous
//
#include <hip/hip_runtime.h>

#define DIM 128
#define CAP 96              // csr slots per node (mean in-deg 32; ovf fallback)
#define BCAP 10240          // region entries per 256-node bucket (mean ~8163, +23 sigma)
#define EPB 4096            // edges per scatter block
#define EPT 16              // edges per thread (EPB/256)
#define GL 16               // lanes per node group in conv kernels (uint2/lane)
#define OVFD_CAP 32768
#define OVFS_CAP 32768

typedef float f32x2 __attribute__((ext_vector_type(2)));

// ---- fp8 e4m3 (OCP, gfx950 HW cvt) helpers ----
template <bool HI>
__device__ __forceinline__ float2 fp8x2_to_f32(unsigned u) {
    f32x2 r = __builtin_amdgcn_cvt_pk_f32_fp8((int)u, HI);
    return make_float2(r.x, r.y);
}
__device__ __forceinline__ unsigned short f32_to_fp8x2(float a, float b) {
    return (unsigned short)(__builtin_amdgcn_cvt_pk_fp8_f32(a, b, 0, false) & 0xFFFF);
}

// Zero the 520-int header (gcursD/gcursS/ovf counters).
__global__ void zero_hdr(int* __restrict__ hdr) {
    int i = threadIdx.x;
    hdr[i] = 0;
    hdr[i + 260] = 0;
    if (i < 8) hdr[i + 512] = 0;
}

// Roles: [0,nb_scat): register-staged counting-sort of EPB edges into 256-node buckets
//        [..,+nb_norm): row L2-normalize features -> fp8 Xb8
//        [..,+nb_copy): preference passthrough (float4)
__global__ void __launch_bounds__(256) prep_kernel(
        const float* __restrict__ features, const float* __restrict__ preference,
        const int* __restrict__ src, const int* __restrict__ dst,
        unsigned short* __restrict__ Xb8,
        unsigned* __restrict__ regionD, unsigned char* __restrict__ regionS,
        int* __restrict__ gcursD, int* __restrict__ gcursS,
        int* __restrict__ ovfD_n, int2* __restrict__ ovfD,
        int* __restrict__ ovfS_n, int* __restrict__ ovfS,
        float* __restrict__ out_pref,
        int N, int E, int NU, int nb, int nb_scat, int nb_norm) {
    __shared__ unsigned histD[256], histS[256];
    __shared__ unsigned scanD[256], scanS[256];
    __shared__ unsigned cursD[256], cursS[256];   // cursors during stage, bases after claim
    __shared__ unsigned wsumD[4], wsumS[4];
    __shared__ unsigned stageD[EPB];              // 16 KB: (bk<<24)|(dLow<<16)|src16
    __shared__ unsigned short stageS[EPB];        // 8 KB: (bk<<8)|sLow
    int b = blockIdx.x, tid = threadIdx.x;

    if (b < nb_scat) {
        int e0 = b * EPB;
        int m = min(E - e0, EPB);
        histD[tid] = 0; histS[tid] = 0;
        unsigned packed[EPT];
        #pragma unroll
        for (int k = 0; k < EPT; ++k) {
            int j = tid + (k << 8);
            packed[k] = 0xFFFFFFFFu;
            if (j < m) {
                int s = src[e0 + j], d = dst[e0 + j];
                if (s != d) packed[k] = ((unsigned)d << 16) | (unsigned)s;
            }
        }
        __syncthreads();
        #pragma unroll
        for (int k = 0; k < EPT; ++k) {
            unsigned pk = packed[k];
            if (pk != 0xFFFFFFFFu) {
                atomicAdd(&histD[(pk >> 24)], 1u);
                atomicAdd(&histS[(pk >> 8) & 0xFFu], 1u);
            }
        }
        __syncthreads();
        {   // parallel exclusive scan of 256 bins (both hists)
            int lane = tid & 63, wid = tid >> 6;
            unsigned vD = histD[tid], vS = histS[tid];
            unsigned iD = vD, iS = vS;
            #pragma unroll
            for (int off = 1; off < 64; off <<= 1) {
                unsigned tD = __shfl_up(iD, off, 64);
                unsigned tS = __shfl_up(iS, off, 64);
                if (lane >= off) { iD += tD; iS += tS; }
            }
            if (lane == 63) { wsumD[wid] = iD; wsumS[wid] = iS; }
            __syncthreads();
            if (tid == 0) { unsigned a = 0; for (int i = 0; i < 4; ++i) { unsigned t = wsumD[i]; wsumD[i] = a; a += t; } }
            if (tid == 64){ unsigned a = 0; for (int i = 0; i < 4; ++i) { unsigned t = wsumS[i]; wsumS[i] = a; a += t; } }
            __syncthreads();
            unsigned eD = iD - vD + wsumD[wid];
            unsigned eS = iS - vS + wsumS[wid];
            scanD[tid] = eD; scanS[tid] = eS;
            cursD[tid] = eD; cursS[tid] = eS;
        }
        __syncthreads();
        #pragma unroll
        for (int k = 0; k < EPT; ++k) {
            unsigned pk = packed[k];
            if (pk != 0xFFFFFFFFu) {
                unsigned bkD = pk >> 24;
                unsigned p = atomicAdd(&cursD[bkD], 1u);
                stageD[p] = (bkD << 24) | ((pk >> 16 & 0xFFu) << 16) | (pk & 0xFFFFu);
                unsigned bkS = (pk >> 8) & 0xFFu;
                unsigned q = atomicAdd(&cursS[bkS], 1u);
                stageS[q] = (unsigned short)((bkS << 8) | (pk & 0xFFu));
            }
        }
        __syncthreads();
        if (tid < nb) {   // claim contiguous global runs (reuse curs as base)
            unsigned c = histD[tid];
            cursD[tid] = c ? (unsigned)atomicAdd(&gcursD[tid], (int)c) : 0u;
            unsigned c2 = histS[tid];
            cursS[tid] = c2 ? (unsigned)atomicAdd(&gcursS[tid], (int)c2) : 0u;
        }
        __syncthreads();
        int mD = (int)(scanD[255] + histD[255]);
        for (int j = tid; j < mD; j += 256) {   // one-pass flush D
            unsigned ent = stageD[j];
            unsigned bk = ent >> 24;
            unsigned gp = cursD[bk] + (unsigned)j - scanD[bk];
            if (gp < BCAP) regionD[(size_t)bk * BCAP + gp] = ent & 0x00FFFFFFu;
            else {
                int o = atomicAdd(ovfD_n, 1);
                if (o < OVFD_CAP) ovfD[o] = make_int2((int)(ent & 0xFFFFu),
                                                      (int)((bk << 8) | ((ent >> 16) & 0xFFu)));
            }
        }
        int mS = (int)(scanS[255] + histS[255]);
        for (int j = tid; j < mS; j += 256) {   // one-pass flush S
            unsigned ent = stageS[j];
            unsigned bk = ent >> 8;
            unsigned gp = cursS[bk] + (unsigned)j - scanS[bk];
            if (gp < BCAP) regionS[(size_t)bk * BCAP + gp] = (unsigned char)(ent & 0xFFu);
            else {
                int o = atomicAdd(ovfS_n, 1);
                if (o < OVFS_CAP) ovfS[o] = (int)ent;
            }
        }
        return;
    }
    b -= nb_scat;
    if (b < nb_norm) {
        int t = b * 256 + tid;
        int row = t >> 6;
        if (row < N) {
            int lane = t & 63;
            float2 v = ((const float2*)(features + (size_t)row * DIM))[lane];
            float ss = v.x * v.x + v.y * v.y;
            #pragma unroll
            for (int off = 32; off >= 1; off >>= 1) ss += __shfl_xor(ss, off, 64);
            float scale = 1.0f / fmaxf(sqrtf(ss), 1e-12f);
            Xb8[(size_t)row * 64 + lane] = f32_to_fp8x2(v.x * scale, v.y * scale);
        }
        return;
    }
    b -= nb_norm;
    {
        int i = b * 256 + tid;
        int n4 = NU * DIM / 4;
        if (i < n4) ((float4*)out_pref)[i] = ((const float4*)preference)[i];
    }
}

// Roles: [0,nb): per-dst-bucket slot assignment -> csr + cnt; [nb,2nb): src-degree -> dis.
__global__ void __launch_bounds__(256) finalize_kernel(
        const unsigned* __restrict__ regionD, const unsigned char* __restrict__ regionS,
        const int* __restrict__ gcursD, const int* __restrict__ gcursS,
        unsigned short* __restrict__ csr, int* __restrict__ cnt, float* __restrict__ dis,
        int* __restrict__ ovfD_n, int2* __restrict__ ovfD,
        const int* __restrict__ ovfS_n, const int* __restrict__ ovfS, int N, int nb) {
    __shared__ unsigned c256[256];
    int b = blockIdx.x, tid = threadIdx.x;
    if (b < nb) {           // dst role
        c256[tid] = 0;
        __syncthreads();
        int m = min(gcursD[b], BCAP);
        for (int j = tid; j < m; j += 256) {
            unsigned ent = regionD[(size_t)b * BCAP + j];
            unsigned dLow = ent >> 16;
            int s = (int)(ent & 0xFFFFu);
            unsigned pos = atomicAdd(&c256[dLow], 1u);
            int node = (b << 8) | (int)dLow;
            if (pos < CAP) csr[(size_t)node * CAP + pos] = (unsigned short)s;
            else {
                int o = atomicAdd(ovfD_n, 1);
                if (o < OVFD_CAP) ovfD[o] = make_int2(s, node);
            }
        }
        __syncthreads();
        int node = (b << 8) | tid;
        if (node < N) cnt[node] = (int)c256[tid];
        return;
    }
    b -= nb;
    {                       // src role
        c256[tid] = 0;
        __syncthreads();
        int m = min(gcursS[b], BCAP);
        for (int j = tid; j < m; j += 256)
            atomicAdd(&c256[regionS[(size_t)b * BCAP + j]], 1u);
        __syncthreads();
        int on = min(*ovfS_n, OVFS_CAP);    // practically 0
        for (int k = tid; k < on; k += 256) {
            int v = ovfS[k];
            if ((v >> 8) == b) atomicAdd(&c256[v & 255], 1u);
        }
        __syncthreads();
        int node = (b << 8) | tid;
        if (node < N) {
            unsigned dg = c256[tid];
            dis[node] = dg ? rsqrtf((float)dg) : 0.0f;
        }
    }
}

// Accumulate 8 dims (one uint2 = 8 fp8) into acc[0..7]
__device__ __forceinline__ void acc8(float (&acc)[8], uint2 uv, float wt) {
    float2 q0 = fp8x2_to_f32<false>(uv.x), q1 = fp8x2_to_f32<true>(uv.x);
    float2 q2 = fp8x2_to_f32<false>(uv.y), q3 = fp8x2_to_f32<true>(uv.y);
    acc[0] += wt * q0.x; acc[1] += wt * q0.y;
    acc[2] += wt * q1.x; acc[3] += wt * q1.y;
    acc[4] += wt * q2.x; acc[5] += wt * q2.y;
    acc[6] += wt * q3.x; acc[7] += wt * q3.y;
}

// 16-lane-group gather, 4-deep edge unroll: 4 independent uint2 row-gathers in
// flight per lane before any consume (round-12 form; preload pipelining removed
// after it cost 8 VGPR and 20% occupancy in round 14).
__device__ __forceinline__ void gather_node16(const uint2* __restrict__ X8,
                                              const unsigned short* __restrict__ csr,
                                              const int* __restrict__ cnt,
                                              const float* __restrict__ dis,
                                              const int* __restrict__ ovfD_n,
                                              const int2* __restrict__ ovfD,
                                              int node, int lane, float (&a)[8]) {
    int c = min(cnt[node], CAP);
    float dd = dis[node];
    size_t base = (size_t)node * CAP;
    float b8[8];
    #pragma unroll
    for (int j = 0; j < 8; ++j) { a[j] = 0.0f; b8[j] = 0.0f; }
    for (int b0 = 0; b0 < c; b0 += GL) {
        int m = min(c - b0, GL);
        int sl = 0; float wl = 0.0f;
        if (lane < m) { sl = csr[base + b0 + lane]; wl = dis[sl] * dd; }
        int i = 0;
        for (; i + 3 < m; i += 4) {
            int s0 = __shfl(sl, i, GL),     s1 = __shfl(sl, i + 1, GL);
            int s2 = __shfl(sl, i + 2, GL), s3 = __shfl(sl, i + 3, GL);
            float w0 = __shfl(wl, i, GL),     w1 = __shfl(wl, i + 1, GL);
            float w2 = __shfl(wl, i + 2, GL), w3 = __shfl(wl, i + 3, GL);
            uint2 u0 = X8[(size_t)s0 * GL + lane];
            uint2 u1 = X8[(size_t)s1 * GL + lane];
            uint2 u2 = X8[(size_t)s2 * GL + lane];
            uint2 u3 = X8[(size_t)s3 * GL + lane];
            acc8(a, u0, w0);
            acc8(b8, u1, w1);
            acc8(a, u2, w2);
            acc8(b8, u3, w3);
        }
        for (; i < m; ++i) {
            int s0 = __shfl(sl, i, GL);
            float w0 = __shfl(wl, i, GL);
            uint2 u0 = X8[(size_t)s0 * GL + lane];
            acc8(a, u0, w0);
        }
    }
    #pragma unroll
    for (int j = 0; j < 8; ++j) a[j] += b8[j];
    int on = min(*ovfD_n, OVFD_CAP);   // practically 0; formal correctness
    for (int k = 0; k < on; ++k) {
        int2 eo = ovfD[k];
        if (eo.y == node) {
            float w = dis[eo.x] * dd;
            uint2 u = X8[(size_t)eo.x * GL + lane];
            acc8(a, u, w);
        }
    }
}

__global__ void __launch_bounds__(256) conv1_kernel(
        const uint2* __restrict__ Xb8, const unsigned short* __restrict__ csr,
        const int* __restrict__ cnt, const float* __restrict__ dis,
        const int* __restrict__ ovfD_n, const int2* __restrict__ ovfD,
        uint2* __restrict__ Hb8, int n) {
    int t = blockIdx.x * 256 + threadIdx.x;
    int node = t >> 4;
    if (node >= n) return;
    int lane = threadIdx.x & (GL - 1);
    float a[8];
    gather_node16(Xb8, csr, cnt, dis, ovfD_n, ovfD, node, lane, a);
    unsigned lo = (unsigned)__builtin_amdgcn_cvt_pk_fp8_f32(a[0], a[1], 0, false);
    lo = (unsigned)__builtin_amdgcn_cvt_pk_fp8_f32(a[2], a[3], (int)lo, true);
    unsigned hi = (unsigned)__builtin_amdgcn_cvt_pk_fp8_f32(a[4], a[5], 0, false);
    hi = (unsigned)__builtin_amdgcn_cvt_pk_fp8_f32(a[6], a[7], (int)hi, true);
    Hb8[(size_t)node * GL + lane] = make_uint2(lo, hi);
}

// out = conv(h) + h + x, with h and x read from the fp8 rows (no features re-read).
__global__ void __launch_bounds__(256) conv2_kernel(
        const uint2* __restrict__ Hb8, const uint2* __restrict__ Xb8,
        const unsigned short* __restrict__ csr,
        const int* __restrict__ cnt, const float* __restrict__ dis,
        const int* __restrict__ ovfD_n, const int2* __restrict__ ovfD,
        float* __restrict__ out, int n) {
    int t = blockIdx.x * 256 + threadIdx.x;
    int node = t >> 4;
    if (node >= n) return;
    int lane = threadIdx.x & (GL - 1);
    float a[8];
    gather_node16(Hb8, csr, cnt, dis, ovfD_n, ovfD, node, lane, a);
    uint2 hu = Hb8[(size_t)node * GL + lane];
    uint2 xu = Xb8[(size_t)node * GL + lane];
    float2 h0 = fp8x2_to_f32<false>(hu.x), h1 = fp8x2_to_f32<true>(hu.x);
    float2 h2 = fp8x2_to_f32<false>(hu.y), h3 = fp8x2_to_f32<true>(hu.y);
    float2 x0 = fp8x2_to_f32<false>(xu.x), x1 = fp8x2_to_f32<true>(xu.x);
    float2 x2 = fp8x2_to_f32<false>(xu.y), x3 = fp8x2_to_f32<true>(xu.y);
    float4 o0, o1;
    o0.x = a[0] + h0.x + x0.x; o0.y = a[1] + h0.y + x0.y;
    o0.z = a[2] + h1.x + x1.x; o0.w = a[3] + h1.y + x1.y;
    o1.x = a[4] + h2.x + x2.x; o1.y = a[5] + h2.y + x2.y;
    o1.z = a[6] + h3.x + x3.x; o1.w = a[7] + h3.y + x3.y;
    float* orow = out + (size_t)node * DIM + lane * 8;
    *(float4*)orow = o0;
    *(float4*)(orow + 4) = o1;
}

extern "C" void kernel_launch(void* const* d_in, const int* in_sizes, int n_in,
                              void* d_out, int out_size, void* d_ws, size_t ws_size,
                              hipStream_t stream) {
    const float* features   = (const float*)d_in[0];
    const float* preference = (const float*)d_in[1];
    const int*   edge_index = (const int*)d_in[2];

    const int N  = in_sizes[0] / DIM;   // 50000
    const int NU = in_sizes[1] / DIM;   // 10000
    const int E  = in_sizes[2] / 2;     // 1600000

    const int* src = edge_index;
    const int* dst = edge_index + E;
    float* out = (float*)d_out;

    const int nb = (N + 255) / 256;     // 196 node buckets

    // workspace layout (~34 MB; ws >= 55 MB proven in round 2)
    char* p = (char*)d_ws;
    unsigned short* Xb8 = (unsigned short*)p; p += (size_t)N * 64 * sizeof(unsigned short);
    unsigned short* Hb8 = (unsigned short*)p; p += (size_t)N * 64 * sizeof(unsigned short);
    unsigned short* csr = (unsigned short*)p; p += (size_t)N * CAP * sizeof(unsigned short);
    unsigned* regionD = (unsigned*)p;         p += (size_t)nb * BCAP * sizeof(unsigned);
    unsigned char* regionS = (unsigned char*)p; p += (size_t)nb * BCAP;
    p = (char*)(((size_t)p + 15) & ~(size_t)15);
    int* cnt = (int*)p;                       p += (size_t)N * sizeof(int);
    float* dis = (float*)p;                   p += (size_t)N * sizeof(float);
    int* hdr = (int*)p;                       p += 520 * sizeof(int);
    int* gcursD = hdr;            // 256 ints
    int* gcursS = hdr + 260;      // 256 ints
    int* ovfD_n = hdr + 516;
    int* ovfS_n = hdr + 517;
    int2* ovfD = (int2*)p;                    p += (size_t)OVFD_CAP * sizeof(int2);
    int* ovfS = (int*)p;                      p += (size_t)OVFS_CAP * sizeof(int);

    zero_hdr<<<1, 256, 0, stream>>>(hdr);

    int nb_scat = (E + EPB - 1) / EPB;
    int nb_norm = (N * 64 + 255) / 256;
    int nb_copy = (NU * DIM / 4 + 255) / 256;
    prep_kernel<<<nb_scat + nb_norm + nb_copy, 256, 0, stream>>>(
        features, preference, src, dst, Xb8, regionD, regionS,
        gcursD, gcursS, ovfD_n, ovfD, ovfS_n, ovfS,
        out + (size_t)N * DIM, N, E, NU, nb, nb_scat, nb_norm);

    finalize_kernel<<<2 * nb, 256, 0, stream>>>(
        regionD, regionS, gcursD, gcursS, csr, cnt, dis,
        ovfD_n, ovfD, ovfS_n, ovfS, N, nb);

    int cblocks = (N * GL + 255) / 256;
    conv1_kernel<<<cblocks, 256, 0, stream>>>((const uint2*)Xb8, csr, cnt, dis,
                                              ovfD_n, ovfD, (uint2*)Hb8, N);
    conv2_kernel<<<cblocks, 256, 0, stream>>>((const uint2*)Hb8, (const uint2*)Xb8,
                                              csr, cnt, dis, ovfD_n, ovfD, out, N);
}